// Round 1
// baseline (211.962 us; speedup 1.0000x reference)
//
#include <hip/hip_runtime.h>
#include <hip/hip_bf16.h>

// Corr: B=4, C=256, H=W=64, HW=4096, TOPK=3, rat_s=0.05 -> sigma=3.2, 2*sigma^2=20.48
// s[m,n] = alpha * (1 - exp(-(dr^2+dc^2)/20.48)) * <xn_m, xn_n>  (symmetric)
// xc[m,n] = exp(2 s[m,n]) / (sm[m] sm[n]),  sm[m] = sum_n exp(s[m,n])
// out[b,k,col] = top-3 over m of xc[m,col]

#define HW 4096
#define CDIM 256
#define INV2S2 0.048828125f  // 1/20.48

typedef __bf16 bf16;
typedef __attribute__((ext_vector_type(8))) __bf16 bf16x8;
typedef __attribute__((ext_vector_type(4))) float f32x4;

#define GAS __attribute__((address_space(1)))
#define LAS __attribute__((address_space(3)))

__device__ __forceinline__ void ins3(float v, float& t0, float& t1, float& t2) {
    float m01 = fminf(t0, v);
    t0 = fmaxf(t0, v);
    float m12 = fminf(t1, m01);
    t1 = fmaxf(t1, m01);
    t2 = fmaxf(t2, m12);
}

// ---------------- normalize + transpose to bf16 xnT[b][pixel][channel] ----------------
__global__ __launch_bounds__(256) void corr_norm(const float* __restrict__ x,
                                                 bf16* __restrict__ xnT) {
    __shared__ float red[4][64];
    __shared__ float invn[64];
    int tid = threadIdx.x;
    int pl = tid & 63, cg = tid >> 6;       // pixel-lane, channel-group
    int P = blockIdx.x * 64 + pl;           // flat index over b*HW
    int b = P >> 12;
    int pix = P & 4095;
    const float* xb = x + ((size_t)(b * CDIM + cg * 64) << 12) + pix;
    float v[64];
    float ss = 0.f;
#pragma unroll
    for (int j = 0; j < 64; ++j) {
        v[j] = xb[(size_t)j << 12];
        ss += v[j] * v[j];
    }
    red[cg][pl] = ss;
    __syncthreads();
    if (tid < 64) {
        float s = red[0][tid] + red[1][tid] + red[2][tid] + red[3][tid];
        invn[tid] = 1.0f / fmaxf(sqrtf(s), 1e-12f);
    }
    __syncthreads();
    float inv = invn[pl];
    bf16* o = xnT + (size_t)P * CDIM + cg * 64;
#pragma unroll
    for (int j0 = 0; j0 < 64; j0 += 8) {
        bf16x8 pk;
#pragma unroll
        for (int j = 0; j < 8; ++j) pk[j] = (bf16)(v[j0 + j] * inv);
        *(bf16x8*)(o + j0) = pk;
    }
}

// ---------------- shared GEMM tile core: 128x128 tile, K=256, 4 waves 2x2 ----------------
__device__ __forceinline__ void gemm_tile(const bf16* __restrict__ xb, int mbase, int nbase,
                                          bf16* As, bf16* Bs, f32x4 (&acc)[4][4]) {
    const int tid = threadIdx.x;
    const int wave = tid >> 6;
    const int lane = tid & 63;
    const int wm = wave >> 1, wn = wave & 1;
    const int l15 = lane & 15, quad = lane >> 4;
#pragma unroll
    for (int mi = 0; mi < 4; ++mi)
#pragma unroll
        for (int ni = 0; ni < 4; ++ni) acc[mi][ni] = (f32x4)0.f;

    for (int k0 = 0; k0 < CDIM; k0 += 32) {
#pragma unroll
        for (int r = 0; r < 2; ++r) {
            int idx = r * 256 + tid;
            int prow = idx >> 2, sub = idx & 3;
            const bf16* gA = xb + ((size_t)(mbase + prow) << 8) + k0 + (sub << 3);
            const bf16* gB = xb + ((size_t)(nbase + prow) << 8) + k0 + (sub << 3);
            bf16* lA = As + ((r * 4 + wave) << 9);  // wave-uniform base, lane*16B appended by HW
            bf16* lB = Bs + ((r * 4 + wave) << 9);
            __builtin_amdgcn_global_load_lds((const GAS void*)gA, (LAS void*)lA, 16, 0, 0);
            __builtin_amdgcn_global_load_lds((const GAS void*)gB, (LAS void*)lB, 16, 0, 0);
        }
        __syncthreads();
        bf16x8 af[4], bfr[4];
#pragma unroll
        for (int i = 0; i < 4; ++i) {
            af[i]  = *(const bf16x8*)(As + (wm * 64 + i * 16 + l15) * 32 + quad * 8);
            bfr[i] = *(const bf16x8*)(Bs + (wn * 64 + i * 16 + l15) * 32 + quad * 8);
        }
#pragma unroll
        for (int mi = 0; mi < 4; ++mi)
#pragma unroll
            for (int ni = 0; ni < 4; ++ni)
                acc[mi][ni] = __builtin_amdgcn_mfma_f32_16x16x32_bf16(af[mi], bfr[ni],
                                                                      acc[mi][ni], 0, 0, 0);
        __syncthreads();
    }
}

// ---------------- pass B: rowsum of exp(s) ----------------
__global__ __launch_bounds__(256) void corr_rowsum(const bf16* __restrict__ xnT,
                                                   const float* __restrict__ alpha_p,
                                                   float* __restrict__ sm) {
    __shared__ __align__(16) bf16 As[128 * 32];
    __shared__ __align__(16) bf16 Bs[128 * 32];
    __shared__ float g1[64];
    int tid = threadIdx.x;
    if (tid < 64) g1[tid] = __expf((float)(tid * tid) * -INV2S2);
    int b = blockIdx.z, mtile = blockIdx.y, ntile = blockIdx.x;
    int mbase = mtile * 128, nbase = ntile * 128;
    f32x4 acc[4][4];
    gemm_tile(xnT + ((size_t)b << 20), mbase, nbase, As, Bs, acc);
    float alpha = alpha_p[0];
    int wave = tid >> 6, lane = tid & 63;
    int wm = wave >> 1, wn = wave & 1, l15 = lane & 15, quad = lane >> 4;
    // wave's 64 m-pixels are one image row; same for n -> row-distance factor is wave-constant
    int rowi = (mbase + wm * 64) >> 6;
    int coli = (nbase + wn * 64) >> 6;
    int adr = rowi - coli; if (adr < 0) adr = -adr;
    float gw = g1[adr];
#pragma unroll
    for (int mi = 0; mi < 4; ++mi) {
#pragma unroll
        for (int r = 0; r < 4; ++r) {
            int rowj = mi * 16 + quad * 4 + r;
            float ssum = 0.f;
#pragma unroll
            for (int ni = 0; ni < 4; ++ni) {
                int colj = ni * 16 + l15;
                int adc = rowj - colj; if (adc < 0) adc = -adc;
                float g = gw * g1[adc];
                float s = alpha * (1.f - g) * acc[mi][ni][r];
                ssum += __expf(s);
            }
            ssum += __shfl_xor(ssum, 1);
            ssum += __shfl_xor(ssum, 2);
            ssum += __shfl_xor(ssum, 4);
            ssum += __shfl_xor(ssum, 8);
            if (l15 == 0)
                atomicAdd(&sm[(b << 12) + mbase + wm * 64 + rowj], ssum);
        }
    }
}

// ---------------- reciprocal ----------------
__global__ __launch_bounds__(256) void corr_recip(const float* __restrict__ sm,
                                                  float* __restrict__ ism) {
    int i = blockIdx.x * 256 + threadIdx.x;
    if (i < 4 * HW) ism[i] = 1.0f / sm[i];
}

// ---------------- pass C: xc + per-tile column top-3 ----------------
__global__ __launch_bounds__(256) void corr_topk(const bf16* __restrict__ xnT,
                                                 const float* __restrict__ alpha_p,
                                                 const float* __restrict__ ism,
                                                 float* __restrict__ wtop) {
    __shared__ __align__(16) bf16 As[128 * 32];
    __shared__ __align__(16) bf16 Bs[128 * 32];
    __shared__ float g1[64];
    __shared__ float mbuf[2][128][3];
    int tid = threadIdx.x;
    if (tid < 64) g1[tid] = __expf((float)(tid * tid) * -INV2S2);
    int b = blockIdx.z, mtile = blockIdx.y, ntile = blockIdx.x;
    int mbase = mtile * 128, nbase = ntile * 128;
    f32x4 acc[4][4];
    gemm_tile(xnT + ((size_t)b << 20), mbase, nbase, As, Bs, acc);
    float a2 = 2.0f * alpha_p[0];
    int wave = tid >> 6, lane = tid & 63;
    int wm = wave >> 1, wn = wave & 1, l15 = lane & 15, quad = lane >> 4;
    int rowi = (mbase + wm * 64) >> 6;
    int coli = (nbase + wn * 64) >> 6;
    int adr = rowi - coli; if (adr < 0) adr = -adr;
    float gw = g1[adr];
    float ismr[4][4];
#pragma unroll
    for (int mi = 0; mi < 4; ++mi)
#pragma unroll
        for (int r = 0; r < 4; ++r)
            ismr[mi][r] = ism[(b << 12) + mbase + wm * 64 + mi * 16 + quad * 4 + r];
#pragma unroll
    for (int ni = 0; ni < 4; ++ni) {
        int colj = ni * 16 + l15;
        float ismc = ism[(b << 12) + nbase + wn * 64 + colj];
        float t0 = 0.f, t1 = 0.f, t2 = 0.f;
#pragma unroll
        for (int mi = 0; mi < 4; ++mi) {
#pragma unroll
            for (int r = 0; r < 4; ++r) {
                int rowj = mi * 16 + quad * 4 + r;
                int adc = rowj - colj; if (adc < 0) adc = -adc;
                float g = gw * g1[adc];
                float e2 = __expf(a2 * (1.f - g) * acc[mi][ni][r]);
                float v = e2 * ismr[mi][r] * ismc;
                ins3(v, t0, t1, t2);
            }
        }
        // merge the 4 quads (disjoint row sets, same column)
#pragma unroll
        for (int d = 16; d <= 32; d <<= 1) {
            float s0 = __shfl_xor(t0, d);
            float s1 = __shfl_xor(t1, d);
            float s2 = __shfl_xor(t2, d);
            ins3(s0, t0, t1, t2);
            ins3(s1, t0, t1, t2);
            ins3(s2, t0, t1, t2);
        }
        if (quad == 0) {
            int cl = wn * 64 + colj;
            mbuf[wm][cl][0] = t0;
            mbuf[wm][cl][1] = t1;
            mbuf[wm][cl][2] = t2;
        }
    }
    __syncthreads();
    if (tid < 128) {
        float t0 = mbuf[0][tid][0], t1 = mbuf[0][tid][1], t2 = mbuf[0][tid][2];
        ins3(mbuf[1][tid][0], t0, t1, t2);
        ins3(mbuf[1][tid][1], t0, t1, t2);
        ins3(mbuf[1][tid][2], t0, t1, t2);
        size_t o = (((size_t)(b * 32 + mtile) << 12) + nbase + tid) * 3;
        wtop[o] = t0;
        wtop[o + 1] = t1;
        wtop[o + 2] = t2;
    }
}

// ---------------- final merge of 32 m-tile partials per column ----------------
__global__ __launch_bounds__(256) void corr_merge(const float* __restrict__ wtop,
                                                  float* __restrict__ out) {
    int idx = blockIdx.x * 256 + threadIdx.x;
    if (idx >= 4 * HW) return;
    int b = idx >> 12, col = idx & 4095;
    float t0 = 0.f, t1 = 0.f, t2 = 0.f;
    for (int mt = 0; mt < 32; ++mt) {
        const float* q = wtop + (((size_t)(b * 32 + mt) << 12) + col) * 3;
        ins3(q[0], t0, t1, t2);
        ins3(q[1], t0, t1, t2);
        ins3(q[2], t0, t1, t2);
    }
    out[((b * 3 + 0) << 12) + col] = t0;
    out[((b * 3 + 1) << 12) + col] = t1;
    out[((b * 3 + 2) << 12) + col] = t2;
}

extern "C" void kernel_launch(void* const* d_in, const int* in_sizes, int n_in,
                              void* d_out, int out_size, void* d_ws, size_t ws_size,
                              hipStream_t stream) {
    const float* x = (const float*)d_in[0];
    const float* alpha = (const float*)d_in[1];
    float* out = (float*)d_out;
    char* ws = (char*)d_ws;
    bf16* xnT = (bf16*)ws;                                   // 8 MB
    float* sm = (float*)(ws + (8u << 20));                   // 64 KB
    float* ism = (float*)(ws + (8u << 20) + (64u << 10));    // 64 KB
    float* wtop = (float*)(ws + (8u << 20) + (128u << 10));  // 6 MB

    hipMemsetAsync(sm, 0, 4 * HW * sizeof(float), stream);
    corr_norm<<<256, 256, 0, stream>>>(x, xnT);
    dim3 g(32, 32, 4);
    corr_rowsum<<<g, 256, 0, stream>>>(xnT, alpha, sm);
    corr_recip<<<64, 256, 0, stream>>>(sm, ism);
    corr_topk<<<g, 256, 0, stream>>>(xnT, alpha, ism, wtop);
    corr_merge<<<64, 256, 0, stream>>>(wtop, out);
}

// Round 2
// 185.981 us; speedup vs baseline: 1.1397x; 1.1397x over previous
//
#include <hip/hip_runtime.h>
#include <hip/hip_bf16.h>

// Corr: B=4, C=256, H=W=64, HW=4096, TOPK=3, rat_s=0.05 -> sigma=3.2, 2*sigma^2=20.48
// s[m,n] = alpha * (1 - exp(-(dr^2+dc^2)/20.48)) * <xn_m, xn_n>  (symmetric)
// xc[m,n] = exp(2 s[m,n]) / (sm[m] sm[n]),  sm[m] = sum_n exp(s[m,n])
// out[b,k,col] = top-3 over m of xc[m,col]
//
// R1: XCD<->batch binding (lin%8 -> batch; each XCD's reads stay in its 4MB L2
//     since one batch's xnT slab is 2MB) + triangular-symmetric rowsum
//     (528 tiles instead of 1024, dual row+col accumulation per tile).

#define HW 4096
#define CDIM 256
#define INV2S2 0.048828125f  // 1/20.48

typedef __bf16 bf16;
typedef __attribute__((ext_vector_type(8))) __bf16 bf16x8;
typedef __attribute__((ext_vector_type(4))) float f32x4;

#define GAS __attribute__((address_space(1)))
#define LAS __attribute__((address_space(3)))

__device__ __forceinline__ void ins3(float v, float& t0, float& t1, float& t2) {
    float m01 = fminf(t0, v);
    t0 = fmaxf(t0, v);
    float m12 = fminf(t1, m01);
    t1 = fmaxf(t1, m01);
    t2 = fmaxf(t2, m12);
}

// triangular decode: t = mt*(mt+1)/2 + nt, nt <= mt
__device__ __forceinline__ void decode_tri(int t, int& mt, int& nt) {
    int m = (int)((sqrtf(8.f * (float)t + 1.f) - 1.f) * 0.5f);
    while ((m + 1) * (m + 2) / 2 <= t) ++m;
    while (m * (m + 1) / 2 > t) --m;
    mt = m;
    nt = t - m * (m + 1) / 2;
}

// ---------------- normalize + transpose to bf16 xnT[b][pixel][channel] ----------------
__global__ __launch_bounds__(256) void corr_norm(const float* __restrict__ x,
                                                 bf16* __restrict__ xnT) {
    __shared__ float red[4][64];
    __shared__ float invn[64];
    int tid = threadIdx.x;
    int pl = tid & 63, cg = tid >> 6;       // pixel-lane, channel-group
    int P = blockIdx.x * 64 + pl;           // flat index over b*HW
    int b = P >> 12;
    int pix = P & 4095;
    const float* xb = x + ((size_t)(b * CDIM + cg * 64) << 12) + pix;
    float v[64];
    float ss = 0.f;
#pragma unroll
    for (int j = 0; j < 64; ++j) {
        v[j] = xb[(size_t)j << 12];
        ss += v[j] * v[j];
    }
    red[cg][pl] = ss;
    __syncthreads();
    if (tid < 64) {
        float s = red[0][tid] + red[1][tid] + red[2][tid] + red[3][tid];
        invn[tid] = 1.0f / fmaxf(sqrtf(s), 1e-12f);
    }
    __syncthreads();
    float inv = invn[pl];
    bf16* o = xnT + (size_t)P * CDIM + cg * 64;
#pragma unroll
    for (int j0 = 0; j0 < 64; j0 += 8) {
        bf16x8 pk;
#pragma unroll
        for (int j = 0; j < 8; ++j) pk[j] = (bf16)(v[j0 + j] * inv);
        *(bf16x8*)(o + j0) = pk;
    }
}

// ---------------- shared GEMM tile core: 128x128 tile, K=256, 4 waves 2x2 ----------------
__device__ __forceinline__ void gemm_tile(const bf16* __restrict__ xb, int mbase, int nbase,
                                          bf16* As, bf16* Bs, f32x4 (&acc)[4][4]) {
    const int tid = threadIdx.x;
    const int wave = tid >> 6;
    const int lane = tid & 63;
    const int wm = wave >> 1, wn = wave & 1;
    const int l15 = lane & 15, quad = lane >> 4;
#pragma unroll
    for (int mi = 0; mi < 4; ++mi)
#pragma unroll
        for (int ni = 0; ni < 4; ++ni) acc[mi][ni] = (f32x4)0.f;

    for (int k0 = 0; k0 < CDIM; k0 += 32) {
#pragma unroll
        for (int r = 0; r < 2; ++r) {
            int idx = r * 256 + tid;
            int prow = idx >> 2, sub = idx & 3;
            const bf16* gA = xb + ((size_t)(mbase + prow) << 8) + k0 + (sub << 3);
            const bf16* gB = xb + ((size_t)(nbase + prow) << 8) + k0 + (sub << 3);
            bf16* lA = As + ((r * 4 + wave) << 9);  // wave-uniform base, lane*16B appended by HW
            bf16* lB = Bs + ((r * 4 + wave) << 9);
            __builtin_amdgcn_global_load_lds((const GAS void*)gA, (LAS void*)lA, 16, 0, 0);
            __builtin_amdgcn_global_load_lds((const GAS void*)gB, (LAS void*)lB, 16, 0, 0);
        }
        __syncthreads();
        bf16x8 af[4], bfr[4];
#pragma unroll
        for (int i = 0; i < 4; ++i) {
            af[i]  = *(const bf16x8*)(As + (wm * 64 + i * 16 + l15) * 32 + quad * 8);
            bfr[i] = *(const bf16x8*)(Bs + (wn * 64 + i * 16 + l15) * 32 + quad * 8);
        }
#pragma unroll
        for (int mi = 0; mi < 4; ++mi)
#pragma unroll
            for (int ni = 0; ni < 4; ++ni)
                acc[mi][ni] = __builtin_amdgcn_mfma_f32_16x16x32_bf16(af[mi], bfr[ni],
                                                                      acc[mi][ni], 0, 0, 0);
        __syncthreads();
    }
}

// ---------------- pass B: rowsum of exp(s), triangular tiles, dual accumulation ----------------
__global__ __launch_bounds__(256) void corr_rowsum(const bf16* __restrict__ xnT,
                                                   const float* __restrict__ alpha_p,
                                                   float* __restrict__ sm) {
    __shared__ __align__(16) bf16 As[128 * 32];
    __shared__ __align__(16) bf16 Bs[128 * 32];
    __shared__ float g1[64];
    int tid = threadIdx.x;
    if (tid < 64) g1[tid] = __expf((float)(tid * tid) * -INV2S2);
    // XCD binding: linear dispatch id % 8 = XCD (round-robin). 2 XCDs per batch.
    int lin = blockIdx.x;
    int xcd = lin & 7;
    int b = xcd >> 1;
    int t = ((lin >> 3) << 1) + (xcd & 1);  // [0, 528)
    int mt, nt;
    decode_tri(t, mt, nt);
    int mbase = mt * 128, nbase = nt * 128;
    f32x4 acc[4][4];
    gemm_tile(xnT + ((size_t)b << 20), mbase, nbase, As, Bs, acc);
    float alpha = alpha_p[0];
    int wave = tid >> 6, lane = tid & 63;
    int wm = wave >> 1, wn = wave & 1, l15 = lane & 15, quad = lane >> 4;
    // wave's 64 m-pixels are one image row; same for n -> row-distance factor is wave-constant
    int rowi = (mbase + wm * 64) >> 6;
    int coli = (nbase + wn * 64) >> 6;
    int adr = rowi - coli; if (adr < 0) adr = -adr;
    float gw = g1[adr];
    float colpart[4] = {0.f, 0.f, 0.f, 0.f};
#pragma unroll
    for (int mi = 0; mi < 4; ++mi) {
#pragma unroll
        for (int r = 0; r < 4; ++r) {
            int rowj = mi * 16 + quad * 4 + r;
            float ssum = 0.f;
#pragma unroll
            for (int ni = 0; ni < 4; ++ni) {
                int colj = ni * 16 + l15;
                int adc = rowj - colj; if (adc < 0) adc = -adc;
                float g = gw * g1[adc];
                float s = alpha * (1.f - g) * acc[mi][ni][r];
                float e = __expf(s);
                ssum += e;
                colpart[ni] += e;
            }
            ssum += __shfl_xor(ssum, 1);
            ssum += __shfl_xor(ssum, 2);
            ssum += __shfl_xor(ssum, 4);
            ssum += __shfl_xor(ssum, 8);
            if (l15 == 0)
                atomicAdd(&sm[(b << 12) + mbase + wm * 64 + rowj], ssum);
        }
    }
    if (mt != nt) {
        // column sums = row sums of the transposed (sub-diagonal) tile
#pragma unroll
        for (int ni = 0; ni < 4; ++ni) {
            float c = colpart[ni];
            c += __shfl_xor(c, 16);
            c += __shfl_xor(c, 32);
            if (quad == 0)
                atomicAdd(&sm[(b << 12) + nbase + wn * 64 + ni * 16 + l15], c);
        }
    }
}

// ---------------- reciprocal ----------------
__global__ __launch_bounds__(256) void corr_recip(const float* __restrict__ sm,
                                                  float* __restrict__ ism) {
    int i = blockIdx.x * 256 + threadIdx.x;
    if (i < 4 * HW) ism[i] = 1.0f / sm[i];
}

// ---------------- pass C: xc + per-tile column top-3 (full grid, XCD-bound) ----------------
__global__ __launch_bounds__(256) void corr_topk(const bf16* __restrict__ xnT,
                                                 const float* __restrict__ alpha_p,
                                                 const float* __restrict__ ism,
                                                 float* __restrict__ wtop) {
    __shared__ __align__(16) bf16 As[128 * 32];
    __shared__ __align__(16) bf16 Bs[128 * 32];
    __shared__ float g1[64];
    __shared__ float mbuf[2][128][3];
    int tid = threadIdx.x;
    if (tid < 64) g1[tid] = __expf((float)(tid * tid) * -INV2S2);
    // XCD binding: lin%8 -> XCD; batch = xcd>>1; tile index mtile-major (A-tile reuse).
    int lin = blockIdx.x;
    int xcd = lin & 7;
    int b = xcd >> 1;
    int t = ((lin >> 3) << 1) + (xcd & 1);  // [0, 1024)
    int mtile = t >> 5, ntile = t & 31;
    int mbase = mtile * 128, nbase = ntile * 128;
    f32x4 acc[4][4];
    gemm_tile(xnT + ((size_t)b << 20), mbase, nbase, As, Bs, acc);
    float a2 = 2.0f * alpha_p[0];
    int wave = tid >> 6, lane = tid & 63;
    int wm = wave >> 1, wn = wave & 1, l15 = lane & 15, quad = lane >> 4;
    int rowi = (mbase + wm * 64) >> 6;
    int coli = (nbase + wn * 64) >> 6;
    int adr = rowi - coli; if (adr < 0) adr = -adr;
    float gw = g1[adr];
    float ismr[4][4];
#pragma unroll
    for (int mi = 0; mi < 4; ++mi)
#pragma unroll
        for (int r = 0; r < 4; ++r)
            ismr[mi][r] = ism[(b << 12) + mbase + wm * 64 + mi * 16 + quad * 4 + r];
#pragma unroll
    for (int ni = 0; ni < 4; ++ni) {
        int colj = ni * 16 + l15;
        float ismc = ism[(b << 12) + nbase + wn * 64 + colj];
        float t0 = 0.f, t1 = 0.f, t2 = 0.f;
#pragma unroll
        for (int mi = 0; mi < 4; ++mi) {
#pragma unroll
            for (int r = 0; r < 4; ++r) {
                int rowj = mi * 16 + quad * 4 + r;
                int adc = rowj - colj; if (adc < 0) adc = -adc;
                float g = gw * g1[adc];
                float e2 = __expf(a2 * (1.f - g) * acc[mi][ni][r]);
                float v = e2 * ismr[mi][r] * ismc;
                ins3(v, t0, t1, t2);
            }
        }
        // merge the 4 quads (disjoint row sets, same column)
#pragma unroll
        for (int d = 16; d <= 32; d <<= 1) {
            float s0 = __shfl_xor(t0, d);
            float s1 = __shfl_xor(t1, d);
            float s2 = __shfl_xor(t2, d);
            ins3(s0, t0, t1, t2);
            ins3(s1, t0, t1, t2);
            ins3(s2, t0, t1, t2);
        }
        if (quad == 0) {
            int cl = wn * 64 + colj;
            mbuf[wm][cl][0] = t0;
            mbuf[wm][cl][1] = t1;
            mbuf[wm][cl][2] = t2;
        }
    }
    __syncthreads();
    if (tid < 128) {
        float t0 = mbuf[0][tid][0], t1 = mbuf[0][tid][1], t2 = mbuf[0][tid][2];
        ins3(mbuf[1][tid][0], t0, t1, t2);
        ins3(mbuf[1][tid][1], t0, t1, t2);
        ins3(mbuf[1][tid][2], t0, t1, t2);
        size_t o = (((size_t)(b * 32 + mtile) << 12) + nbase + tid) * 3;
        wtop[o] = t0;
        wtop[o + 1] = t1;
        wtop[o + 2] = t2;
    }
}

// ---------------- final merge of 32 m-tile partials per column ----------------
__global__ __launch_bounds__(256) void corr_merge(const float* __restrict__ wtop,
                                                  float* __restrict__ out) {
    int idx = blockIdx.x * 256 + threadIdx.x;
    if (idx >= 4 * HW) return;
    int b = idx >> 12, col = idx & 4095;
    float t0 = 0.f, t1 = 0.f, t2 = 0.f;
    for (int mt = 0; mt < 32; ++mt) {
        const float* q = wtop + (((size_t)(b * 32 + mt) << 12) + col) * 3;
        ins3(q[0], t0, t1, t2);
        ins3(q[1], t0, t1, t2);
        ins3(q[2], t0, t1, t2);
    }
    out[((b * 3 + 0) << 12) + col] = t0;
    out[((b * 3 + 1) << 12) + col] = t1;
    out[((b * 3 + 2) << 12) + col] = t2;
}

extern "C" void kernel_launch(void* const* d_in, const int* in_sizes, int n_in,
                              void* d_out, int out_size, void* d_ws, size_t ws_size,
                              hipStream_t stream) {
    const float* x = (const float*)d_in[0];
    const float* alpha = (const float*)d_in[1];
    float* out = (float*)d_out;
    char* ws = (char*)d_ws;
    bf16* xnT = (bf16*)ws;                                   // 8 MB
    float* sm = (float*)(ws + (8u << 20));                   // 64 KB
    float* ism = (float*)(ws + (8u << 20) + (64u << 10));    // 64 KB
    float* wtop = (float*)(ws + (8u << 20) + (128u << 10));  // 6 MB

    hipMemsetAsync(sm, 0, 4 * HW * sizeof(float), stream);
    corr_norm<<<256, 256, 0, stream>>>(x, xnT);
    corr_rowsum<<<528 * 4, 256, 0, stream>>>(xnT, alpha, sm);
    corr_recip<<<64, 256, 0, stream>>>(sm, ism);
    corr_topk<<<1024 * 4, 256, 0, stream>>>(xnT, alpha, ism, wtop);
    corr_merge<<<64, 256, 0, stream>>>(wtop, out);
}